// Round 16
// baseline (166.436 us; speedup 1.0000x reference)
//
#include <hip/hip_runtime.h>
#include <hip/hip_bf16.h>

#define NL    64
#define DIN   512
#define DOUT  512
#define BATCH 1024

#define BM 64
#define BN 512            // full DOUT
#define BK 32
#define NK (DIN / BK)     // 16
#define BLDSS 40          // B col stride in shorts (80 B)
#define ASH (BM * DIN)    // A shorts: 32768 (64 KB)
#define BSH (BN * BLDSS)  // B shorts per buf: 20480 (40 KB)

typedef short short8 __attribute__((ext_vector_type(8)));
typedef float f32x4  __attribute__((ext_vector_type(4)));

__device__ __forceinline__ unsigned int pk2(float a, float b) {
    // v_cvt_pk_bf16_f32 (RNE)
    __hip_bfloat162 h = __float22bfloat162_rn(make_float2(a, b));
    unsigned int r;
    __builtin_memcpy(&r, &h, 4);
    return r;
}

__global__ __launch_bounds__(512) void nlinear_kernel(
        const float* __restrict__ x, const float* __restrict__ w,
        const float* __restrict__ bias, float* __restrict__ out) {
    // A: [64][512] bf16, 1024B rows = 64 x 16B slots, slot stored at s^(row&7).
    //    Staged ONCE (x read once, 2KB-contiguous per row). Read-only after.
    // B: [512][40] bf16 (R14 layout), double-buffered, staged per K-step.
    extern __shared__ unsigned short lds[];
    unsigned short* const Asm = lds;           // 32768 shorts
    unsigned short* const Bsm = lds + ASH;     // 2 x 20480 shorts

    const int tid = threadIdx.x;
    const int bid = blockIdx.x;
    // 1024 blocks = 8 XCDs x 128; 16 consecutive blocks share one layer's w.
    const int nb    = (bid & 7) * 128 + (bid >> 3);
    const int layer = nb >> 4;
    const int bm0   = (nb & 15) * BM;

    const int lane = tid & 63;
    const int wc   = tid >> 6;          // wave 0..7 owns cols wc*64..+63
    const int lrow = lane & 15;
    const int lkb  = lane >> 4;         // k-octet 0..3

    // A-stage: 8 threads/row, thread owns 64 consecutive floats (8 slots)
    const int arow = tid >> 3;          // 0..63
    const int ac8  = tid & 7;
    // B-stage: wave gw owns k-quad gw (4 k); lane gc owns 8 cols gc*8+j
    const int gw = tid >> 6;
    const int gc = tid & 63;

    const size_t XS = (size_t)NL * DIN;
    const float* aptr = x + (size_t)(bm0 + arow) * XS + (size_t)layer * DIN;
    const float* wb   = w + (size_t)layer * DIN * DOUT;
    const float* bptr = wb + (size_t)(gw * 4) * DOUT + gc * 8;

    f32x4 acc[4][4];
#pragma unroll
    for (int i = 0; i < 4; ++i)
#pragma unroll
        for (int j = 0; j < 4; ++j) acc[i][j] = (f32x4){0.f, 0.f, 0.f, 0.f};

    f32x4 bvr[4][2];   // B flight: 4 k-rows x 8 cols

    auto issueB = [&](int t) {
#pragma unroll
        for (int ki = 0; ki < 4; ++ki) {
            const float* p = bptr + (size_t)(t * BK + ki) * DOUT;
            bvr[ki][0] = *reinterpret_cast<const f32x4*>(p);
            bvr[ki][1] = *reinterpret_cast<const f32x4*>(p + 4);
        }
    };
    auto cvtwriteB = [&](int db) {
        unsigned short* dst = Bsm + db * BSH;
#pragma unroll
        for (int j = 0; j < 8; ++j) {
            const int c = gc * 8 + j;
            const int h = j >> 2, e = j & 3;
            uint2 wv;
            wv.x = pk2(bvr[0][h][e], bvr[1][h][e]);
            wv.y = pk2(bvr[2][h][e], bvr[3][h][e]);
            const int slot = gw ^ ((c >> 2) & 7);
            *reinterpret_cast<uint2*>(&dst[c * BLDSS + slot * 4]) = wv;
        }
    };

    auto fragA = [&](int t, short8* af) {
#pragma unroll
        for (int mi = 0; mi < 4; ++mi) {
            const int row = mi * 16 + lrow;
            const int s   = t * 4 + lkb;
            af[mi] = *reinterpret_cast<const short8*>(
                &Asm[row * DIN + ((s ^ (row & 7)) << 3)]);
        }
    };
    auto fragB = [&](int db, short8* bf) {
        const unsigned short* src = Bsm + db * BSH;
#pragma unroll
        for (int ni = 0; ni < 4; ++ni) {
            const int col = wc * 64 + ni * 16 + lrow;
            const int key = (col >> 2) & 7;
            const unsigned short* base = &src[col * BLDSS];
            uint2 lo = *reinterpret_cast<const uint2*>(
                base + (((2 * lkb) ^ key) << 2));
            uint2 hi = *reinterpret_cast<const uint2*>(
                base + (((2 * lkb + 1) ^ key) << 2));
            uint4 u = make_uint4(lo.x, lo.y, hi.x, hi.y);
            __builtin_memcpy(&bf[ni], &u, 16);
        }
    };

#define BARRIER() do { \
        asm volatile("s_waitcnt lgkmcnt(0)" ::: "memory"); \
        __builtin_amdgcn_sched_barrier(0); \
        __builtin_amdgcn_s_barrier(); \
        __builtin_amdgcn_sched_barrier(0); } while (0)

#define COMPUTE(T, DB) do { \
        short8 af[4], bf[4]; \
        fragA(T, af); \
        fragB(DB, bf); \
        asm volatile("s_waitcnt lgkmcnt(0)" ::: "memory"); \
        __builtin_amdgcn_sched_barrier(0); \
        __builtin_amdgcn_s_setprio(1); \
        _Pragma("unroll") \
        for (int mi = 0; mi < 4; ++mi) \
        _Pragma("unroll") \
            for (int ni = 0; ni < 4; ++ni) \
                acc[mi][ni] = __builtin_amdgcn_mfma_f32_16x16x32_bf16( \
                    af[mi], bf[ni], acc[mi][ni], 0, 0, 0); \
        __builtin_amdgcn_s_setprio(0); \
        __builtin_amdgcn_sched_barrier(0); } while (0)

    // ---- prologue: B(0) first (flight), then stage A whole-K (x once) ----
    issueB(0);
    {
        // 8 pass-pairs: thread reads 8 consecutive floats, writes one 16B slot
#pragma unroll
        for (int i = 0; i < 8; ++i) {
            const float* p = aptr + i * 64 + ac8 * 8;
            f32x4 v0 = *reinterpret_cast<const f32x4*>(p);
            f32x4 v1 = *reinterpret_cast<const f32x4*>(p + 4);
            uint4 wv;
            wv.x = pk2(v0[0], v0[1]);
            wv.y = pk2(v0[2], v0[3]);
            wv.z = pk2(v1[0], v1[1]);
            wv.w = pk2(v1[2], v1[3]);
            const int s = i * 8 + ac8;
            *reinterpret_cast<uint4*>(
                &Asm[arow * DIN + ((s ^ (arow & 7)) << 3)]) = wv;
        }
    }
    cvtwriteB(0);
    issueB(1);
    BARRIER();

    // ---- K-loop: only B staged; A read-only; 1 barrier/step ----
#pragma unroll 1
    for (int t = 0; t < NK - 2; ++t) {
        COMPUTE(t, t & 1);
        cvtwriteB((t + 1) & 1);
        issueB(t + 2);
        BARRIER();
    }
    {   // t = NK-2: stage last B tile
        COMPUTE(NK - 2, (NK - 2) & 1);
        cvtwriteB((NK - 1) & 1);
        BARRIER();
    }
    {   // t = NK-1: compute only
        COMPUTE(NK - 1, (NK - 1) & 1);
    }

    // ---- epilogue: + bias, fp32 store ----
    const float* bb = bias + (size_t)layer * DOUT;
    float* ob = out + (size_t)bm0 * (NL * DOUT) + (size_t)layer * DOUT;
#pragma unroll
    for (int mi = 0; mi < 4; ++mi) {
#pragma unroll
        for (int ni = 0; ni < 4; ++ni) {
            const int col = wc * 64 + ni * 16 + lrow;
            const float bval = bb[col];
#pragma unroll
            for (int r = 0; r < 4; ++r) {
                const int row = mi * 16 + lkb * 4 + r;
                ob[(size_t)row * (NL * DOUT) + col] = acc[mi][ni][r] + bval;
            }
        }
    }
#undef BARRIER
#undef COMPUTE
}

extern "C" void kernel_launch(void* const* d_in, const int* in_sizes, int n_in,
                              void* d_out, int out_size, void* d_ws, size_t ws_size,
                              hipStream_t stream) {
    const float* x  = (const float*)d_in[0];
    const float* w  = (const float*)d_in[1];
    const float* b  = (const float*)d_in[2];
    float* out      = (float*)d_out;

    const int lds_bytes = (ASH + 2 * BSH) * 2;   // 147456
    hipFuncSetAttribute((const void*)nlinear_kernel,
                        hipFuncAttributeMaxDynamicSharedMemorySize, lds_bytes);

    dim3 grid(NL * (BATCH / BM));   // 64 * 16 = 1024
    dim3 block(512);
    hipLaunchKernelGGL(nlinear_kernel, grid, block, lds_bytes, stream,
                       x, w, b, out);
}